// Round 15
// baseline (251.546 us; speedup 1.0000x reference)
//
#include <hip/hip_runtime.h>

#define NB 16
#define NC 256
#define HW 2304
#define CHW 589824  // NC*HW

typedef __attribute__((ext_vector_type(8))) short bf16x8;
typedef __attribute__((ext_vector_type(16))) float f32x16;

union BF8 { bf16x8 v; unsigned short u[8]; unsigned d[4]; };

__device__ inline unsigned short f2bf(float f) {
  unsigned u = __builtin_bit_cast(unsigned, f);
  u += 0x7fffu + ((u >> 16) & 1u);  // RNE (inputs finite)
  return (unsigned short)(u >> 16);
}

// packed f32x2 -> bf16x2 (RNE), gfx950 v_cvt_pk_bf16_f32 (no builtin; value-producing asm).
__device__ inline unsigned f2bf2(float lo, float hi) {
  unsigned r;
  asm("v_cvt_pk_bf16_f32 %0, %1, %2" : "=v"(r) : "v"(lo), "v"(hi));
  return r;
}

// ================= K1: prep — xtpack only (wpack eliminated R15; x1pack eliminated R13) =================
// xtp[b][mb][f][l][j] = x[b][k = 16f+8*(l>>5)+j][m = 32mb + (l&31)]   (+ sumsq partials, 144/b)
__global__ __launch_bounds__(256) void prep_kernel(const float* __restrict__ x,
                                                   unsigned short* __restrict__ xtp,
                                                   double* __restrict__ partials) {
  __shared__ __align__(16) char smem[17440];
  const int e = blockIdx.x;
  const int tid = threadIdx.x;
  const int mt = e % 36, kt = (e / 36) % 4, b = e / 144;
  const int m0 = mt * 64, k0 = kt * 64;
  float* tile = (float*)smem;              // [64][68] floats = 17408 B
  double* red = (double*)(smem + 17408);   // [4]
  const float* xb = x + (size_t)b * CHW;
  double ss = 0.0;
  #pragma unroll
  for (int it = 0; it < 4; ++it) {
    const int i = tid + 256 * it;
    const int row = i >> 4, c4 = (i & 15) * 4;
    float4 v = *(const float4*)(xb + (size_t)(k0 + row) * HW + m0 + c4);
    *(float4*)&tile[row * 68 + c4] = v;
    ss += (double)v.x * v.x + (double)v.y * v.y + (double)v.z * v.z + (double)v.w * v.w;
  }
  #pragma unroll
  for (int off = 32; off > 0; off >>= 1) ss += __shfl_down(ss, off, 64);
  const int w = tid >> 6, l = tid & 63;
  if (l == 0) red[w] = ss;
  __syncthreads();
  if (tid == 0) partials[b * 144 + kt * 36 + mt] = red[0] + red[1] + red[2] + red[3];
  const int l31 = l & 31, h = l >> 5;
  unsigned short* dst = xtp + (size_t)b * CHW;
  #pragma unroll
  for (int pp = 0; pp < 2; ++pp) {
    const int p = 2 * w + pp, mbl = p >> 2, fl = p & 3;
    BF8 o;
    #pragma unroll
    for (int jj = 0; jj < 4; ++jj) {
      const float e0 = tile[(16 * fl + 8 * h + 2 * jj) * 68 + 32 * mbl + l31];
      const float e1 = tile[(16 * fl + 8 * h + 2 * jj + 1) * 68 + 32 * mbl + l31];
      o.d[jj] = f2bf2(e0, e1);
    }
    const int mb = 2 * mt + mbl, f = 4 * kt + fl;
    *(bf16x8*)(dst + (((size_t)mb * 16 + f) * 64 + l) * 8) = o.v;
  }
}

// ================= K2: conv3 — split by (b, rt, cb8); 1024 blocks x 576 thr (9 waves) R15 =================
// Emission identity: unit (kfi, cb8) reads reshape cols c in [32cb8,+32) -> only mb = 8s+cb8.
// Wave w owns s = w: 16 MFMAs -> LDS tile row-band; emission 2 kfi units/wave (coalesced 1KB).
// R15: af built DIRECTLY from W (af[f][l] = 8 contiguous floats of W row 32rt+(l&31)) -- wp
// and the wpack producer are gone. W (256 KB) is L2/L3-hot (128 blocks share each rt).
__global__ __launch_bounds__(576) void conv3_kernel(const float* __restrict__ W,
                                                    const float* __restrict__ bias,
                                                    const unsigned short* __restrict__ xtp,
                                                    unsigned short* __restrict__ trp,
                                                    const double* __restrict__ partials,
                                                    float* __restrict__ inv_xn2) {
  const int bid = blockIdx.x;
  if (bid == 1024) {  // ---- finish role: 1/xn^2 per batch ----
    const int t = threadIdx.x;
    if (t >= 128) return;
    const int b = t >> 3, i0 = t & 7;
    double v = 0.0;
    for (int i = i0; i < 144; i += 8) v += partials[b * 144 + i];
    v += __shfl_down(v, 4, 64);
    v += __shfl_down(v, 2, 64);
    v += __shfl_down(v, 1, 64);
    if (i0 == 0) inv_xn2[b] = (float)(1.0 / v);
    return;
  }
  const int xcd = bid & 7, r = bid >> 3;      // r in [0,128)
  const int b = xcd + 8 * (r & 1);            // 2 batches per XCD -> xtp[b] L2-resident
  const int r2 = r >> 1;                      // [0,64)
  const int rt = r2 >> 3, cb8 = r2 & 7;       // c'-tile of 32, c-col group of 32
  const int tid = threadIdx.x, w = tid >> 6, l = tid & 63, l31 = l & 31, h = l >> 5;
  const unsigned short* xb = xtp + (size_t)b * CHW;

  __shared__ unsigned short tile[32 * 296];   // [c'_local][32*s + l31, +8 pad]

  // A-frags direct from W: af[f] = W[32rt + l31][16f + 8h .. +8]  (8 contiguous floats)
  bf16x8 af[16];
  {
    const float* wrow = W + (size_t)(32 * rt + l31) * 256 + 8 * h;
    #pragma unroll
    for (int f = 0; f < 16; ++f) {
      const float4 r0 = *(const float4*)(wrow + 16 * f);
      const float4 r1 = *(const float4*)(wrow + 16 * f + 4);
      BF8 o;
      o.d[0] = f2bf2(r0.x, r0.y);
      o.d[1] = f2bf2(r0.z, r0.w);
      o.d[2] = f2bf2(r1.x, r1.y);
      o.d[3] = f2bf2(r1.z, r1.w);
      af[f] = o.v;
    }
  }
  // bias per accumulator register
  float bcol[16];
  #pragma unroll
  for (int reg = 0; reg < 16; ++reg) {
    const int rowl = (reg & 3) + 8 * (reg >> 2) + 4 * h;
    bcol[reg] = bias[32 * rt + rowl];
  }

  // ---- MFMA phase: wave w owns s = w; mb = 8s + cb8; 16 MFMAs ----
  {
    const int s = w;
    const int mb = 8 * s + cb8;
    f32x16 acc;
    #pragma unroll
    for (int rr = 0; rr < 16; ++rr) acc[rr] = 0.f;
    #pragma unroll
    for (int f = 0; f < 16; ++f) {
      bf16x8 bv = *(const bf16x8*)(xb + (((size_t)mb * 16 + f) * 64 + l) * 8);
      acc = __builtin_amdgcn_mfma_f32_32x32x16_bf16(af[f], bv, acc, 0, 0, 0);
    }
    #pragma unroll
    for (int p = 0; p < 8; ++p) {
      const int r0 = 2 * p, r1 = 2 * p + 1;
      const int rowl = (r0 & 3) + 8 * (r0 >> 2) + 4 * h;  // r1's row = rowl + 1
      const unsigned pk = f2bf2(acc[r0] + bcol[r0], acc[r1] + bcol[r1]);
      tile[rowl * 296 + 32 * s + l31] = (unsigned short)pk;
      tile[(rowl + 1) * 296 + 32 * s + l31] = (unsigned short)(pk >> 16);
    }
  }
  __syncthreads();

  // ---- emission phase: 18 kfi units, 2 per wave; unit = coalesced 1KB trp store ----
  unsigned short* tb = trp + (size_t)b * CHW;
  #pragma unroll
  for (int si = 0; si < 2; ++si) {
    const int kfi = 2 * w + si;
    const int mbase = 288 * rt + 16 * kfi;     // 16-aligned reshaped-row base
    const int mb2 = mbase >> 6, kf = (mbase >> 4) & 3;
    BF8 o;
    #pragma unroll
    for (int j = 0; j < 8; ++j) {
      const int m = mbase + 8 * h + j;         // reshaped row
      const int a = m / 9, s = m - 9 * a;      // c' = a, band = s
      o.u[j] = tile[(a - 32 * rt) * 296 + 32 * s + l31];
    }
    *(bf16x8*)(tb + (size_t)mb2 * 16384 + (((size_t)cb8 * 4 + kf) * 64 + l) * 8) = o.v;
  }
}

// ================= K4: fused — R2-v3 schedule (CLOSED) + direct-x Af staging (R13) =================
// v3 core untouched: dbuf Pl, 1 barrier/chunk, reg-dbuf bv prefetch, LB(256,2), VGPR 128.
// Failed challengers (do not retry): sched_barrier/asm-waitcnt (R3 spill), setprio (R4 -8%),
// half-Af (R7 spill), single-Pl+LB3 (R8 spill), n128/4x-reuse (R10 -28%), single-Pl+LB2
// (R11 +7us). Cross-round noise band on this kernel: +-4-7us (R13 122.8 vs R14 129.7, same code).
#define CHUNK_BODY(CH, CUR, NXT)                                                                   \
  {                                                                                                \
    const int ch_ = (CH);                                                                          \
    const int pb_ = ch_ & 1;                                                                       \
    f32x16 s0, s1;                                                                                 \
    _Pragma("unroll")                                                                              \
    for (int i = 0; i < 16; ++i) { s0[i] = 0.f; s1[i] = 0.f; }                                     \
    _Pragma("unroll")                                                                              \
    for (int f = 0; f < 16; ++f) {                                                                 \
      bf16x8 a0 = *(const bf16x8*)(Af + f * 512 + lane * 8);                                       \
      bf16x8 a1 = *(const bf16x8*)(Af + (16 + f) * 512 + lane * 8);                                \
      s0 = __builtin_amdgcn_mfma_f32_32x32x16_bf16(a0, CUR[f], s0, 0, 0, 0);                       \
      s1 = __builtin_amdgcn_mfma_f32_32x32x16_bf16(a1, CUR[f], s1, 0, 0, 0);                       \
    }                                                                                              \
    bf16x8 bt0[8], bt1[8];                                                                         \
    _Pragma("unroll")                                                                              \
    for (int kk = 0; kk < 8; ++kk) {                                                               \
      const size_t mb_ = 2 * ch_ + (kk >> 2);                                                      \
      bt0[kk] = *(const bf16x8*)(ttb + mb_ * 16384 + ((size_t)((2 * c) * 4 + (kk & 3))) * 512 + lane * 8);     \
      bt1[kk] = *(const bf16x8*)(ttb + mb_ * 16384 + ((size_t)((2 * c + 1) * 4 + (kk & 3))) * 512 + lane * 8); \
    }                                                                                              \
    _Pragma("unroll")                                                                              \
    for (int reg = 0; reg < 16; ++reg) {                                                           \
      const int rowp = (reg & 3) + 8 * (reg >> 2) + 4 * h;                                         \
      float v0 = fmaxf(s0[reg] * inv2, 0.f); v0 *= v0;                                             \
      float v1 = fmaxf(s1[reg] * inv2, 0.f); v1 *= v1;                                             \
      Pl[pb_][rowp][32 * c + l31] = f2bf(v0);                                                      \
      Pl[pb_][32 + rowp][32 * c + l31] = f2bf(v1);                                                 \
    }                                                                                              \
    const int chn_ = (ch_ < 17) ? ch_ + 1 : 17;                                                    \
    const unsigned short* bpn_ = xtb + (size_t)((4 * chn_ + c) * 16) * 512 + lane * 8;             \
    _Pragma("unroll")                                                                              \
    for (int f = 0; f < 16; ++f) NXT[f] = *(const bf16x8*)(bpn_ + f * 512);                        \
    __syncthreads();                                                                               \
    _Pragma("unroll")                                                                              \
    for (int kk = 0; kk < 8; ++kk) {                                                               \
      bf16x8 pf0 = *(const bf16x8*)&Pl[pb_][l31][16 * kk + 8 * h];                                 \
      bf16x8 pf1 = *(const bf16x8*)&Pl[pb_][32 + l31][16 * kk + 8 * h];                            \
      yacc[0][0] = __builtin_amdgcn_mfma_f32_32x32x16_bf16(pf0, bt0[kk], yacc[0][0], 0, 0, 0);     \
      yacc[1][0] = __builtin_amdgcn_mfma_f32_32x32x16_bf16(pf1, bt0[kk], yacc[1][0], 0, 0, 0);     \
      yacc[0][1] = __builtin_amdgcn_mfma_f32_32x32x16_bf16(pf0, bt1[kk], yacc[0][1], 0, 0, 0);     \
      yacc[1][1] = __builtin_amdgcn_mfma_f32_32x32x16_bf16(pf1, bt1[kk], yacc[1][1], 0, 0, 0);     \
    }                                                                                              \
  }

__global__ __launch_bounds__(256, 2) void fused_kernel(const float* __restrict__ x,
                                                       const unsigned short* __restrict__ xtp,
                                                       const unsigned short* __restrict__ trp,
                                                       const float* __restrict__ inv_xn2,
                                                       float* __restrict__ out) {
  const int bid = blockIdx.x;
  const int xcd = bid & 7, j = bid >> 3;     // j in [0,72)
  const int hi = (j >= 36) ? 1 : 0;
  const int b = xcd + 8 * hi;                // one batch per XCD at a time
  const int nt = j - 36 * hi;                // [0,36) n-tile of 64 rows
  const float* xsrc = x + (size_t)b * CHW;
  const unsigned short* xtb = xtp + (size_t)b * CHW;
  const unsigned short* ttb = trp + (size_t)b * CHW;
  float* ob = out + (size_t)b * CHW;
  const float inv2 = inv_xn2[b];

  const int tid = threadIdx.x;
  const int c = tid >> 6, lane = tid & 63;   // wave c = S-col / Y-col group
  const int l31 = lane & 31, h = lane >> 5;

  __shared__ unsigned short Af[16384];       // 2 n-halves x 16 A-frags x 512 shorts (32 KB)
  __shared__ unsigned short Pl[2][64][136];  // double-buffered P (34.0 KB)

  {  // stage Af DIRECTLY from x: fragment (f,l) = 32 contiguous bytes of x at
     // row n = 64*nt + 32*(f>>4) + (l&31), col 16*(f&15) + 8*(l>>5)   [R13]
    #pragma unroll
    for (int it = 0; it < 8; ++it) {
      const int idx = tid + 256 * it;        // [0,2048) = (f in [0,32)) x (l in [0,64))
      const int f = idx >> 6, l = idx & 63;
      const int ll31 = l & 31, hh = l >> 5;
      const float* sp = xsrc + (size_t)(64 * nt + 32 * (f >> 4) + ll31) * 256 + 16 * (f & 15) + 8 * hh;
      const float4 r0 = *(const float4*)sp;
      const float4 r1 = *(const float4*)(sp + 4);
      BF8 o;
      o.d[0] = f2bf2(r0.x, r0.y);
      o.d[1] = f2bf2(r0.z, r0.w);
      o.d[2] = f2bf2(r1.x, r1.y);
      o.d[3] = f2bf2(r1.z, r1.w);
      *(bf16x8*)(Af + (size_t)f * 512 + (size_t)l * 8) = o.v;
    }
  }

  // prologue: chunk 0's S B-frags (issued before the staging barrier; independent of LDS)
  bf16x8 bva[16], bvb[16];
  {
    const unsigned short* bp0 = xtb + (size_t)(c * 16) * 512 + lane * 8;
    #pragma unroll
    for (int f = 0; f < 16; ++f) bva[f] = *(const bf16x8*)(bp0 + f * 512);
  }
  __syncthreads();

  f32x16 yacc[2][2];  // [n-half][cb]
  #pragma unroll
  for (int nh = 0; nh < 2; ++nh)
    #pragma unroll
    for (int cb = 0; cb < 2; ++cb)
      #pragma unroll
      for (int i = 0; i < 16; ++i) yacc[nh][cb][i] = 0.f;

  for (int ci = 0; ci < 9; ++ci) {  // 18 chunks, explicit 2x alternation of bva/bvb (rule #20)
    CHUNK_BODY(2 * ci, bva, bvb)
    CHUNK_BODY(2 * ci + 1, bvb, bva)
  }

  // ---- epilogue: out flat at ob[n*256 + k'] ----
  #pragma unroll
  for (int nh = 0; nh < 2; ++nh)
    #pragma unroll
    for (int cb = 0; cb < 2; ++cb) {
      const int col = 64 * c + 32 * cb + l31;
      #pragma unroll
      for (int reg = 0; reg < 16; ++reg) {
        const int rowp = (reg & 3) + 8 * (reg >> 2) + 4 * h;
        ob[(size_t)(64 * nt + 32 * nh + rowp) * NC + col] = yacc[nh][cb][reg];
      }
    }
}

extern "C" void kernel_launch(void* const* d_in, const int* in_sizes, int n_in,
                              void* d_out, int out_size, void* d_ws, size_t ws_size,
                              hipStream_t stream) {
  const float* x    = (const float*)d_in[0];
  const float* W    = (const float*)d_in[1];
  const float* bias = (const float*)d_in[2];
  float* out = (float*)d_out;

  const size_t SZ = (size_t)NB * CHW * sizeof(unsigned short);  // 18,874,368 B
  double* partials       = (double*)d_ws;                           // 16*144*8 = 18,432 B
  float* inv_xn2         = (float*)((char*)d_ws + 24576);
  unsigned short* xtp    = (unsigned short*)((char*)d_ws + 163840 + SZ);
  unsigned short* trp    = (unsigned short*)((char*)d_ws + 163840 + 3 * SZ);

  prep_kernel<<<2304, 256, 0, stream>>>(x, xtp, partials);
  conv3_kernel<<<1025, 576, 0, stream>>>(W, bias, xtp, trp, partials, inv_xn2);
  fused_kernel<<<576, 256, 0, stream>>>(x, xtp, trp, inv_xn2, out);
}

// Round 16
// 216.879 us; speedup vs baseline: 1.1598x; 1.1598x over previous
//
#include <hip/hip_runtime.h>

#define NB 16
#define NC 256
#define HW 2304
#define CHW 589824  // NC*HW

typedef __attribute__((ext_vector_type(8))) short bf16x8;
typedef __attribute__((ext_vector_type(16))) float f32x16;

union BF8 { bf16x8 v; unsigned short u[8]; unsigned d[4]; };

__device__ inline unsigned short f2bf(float f) {
  unsigned u = __builtin_bit_cast(unsigned, f);
  u += 0x7fffu + ((u >> 16) & 1u);  // RNE (inputs finite)
  return (unsigned short)(u >> 16);
}

// packed f32x2 -> bf16x2 (RNE), gfx950 v_cvt_pk_bf16_f32 (no builtin; value-producing asm).
__device__ inline unsigned f2bf2(float lo, float hi) {
  unsigned r;
  asm("v_cvt_pk_bf16_f32 %0, %1, %2" : "=v"(r) : "v"(lo), "v"(hi));
  return r;
}

// ================= K1: prep (wpack + xtpack) — R16: wpack RESTORED =================
// R15 lesson: W-direct af in conv3 re-read 288 MB of unpacked W (every wave redoing wpack's
// work); the 8-block wpack dedup is worth its launch cost. x1pack remains eliminated (R13).
// wp[rt][f][l][j]  = W[32rt + (l&31)][16f + 8*(l>>5) + j]
// xtp[b][mb][f][l][j] = x[b][k = 16f+8*(l>>5)+j][m = 32mb + (l&31)]   (+ sumsq, 144/b)
__global__ __launch_bounds__(256) void prep_kernel(const float* __restrict__ x,
                                                   const float* __restrict__ W,
                                                   unsigned short* __restrict__ wp,
                                                   unsigned short* __restrict__ xtp,
                                                   double* __restrict__ partials) {
  __shared__ __align__(16) char smem[33344];
  const int bid = blockIdx.x;
  const int tid = threadIdx.x;

  if (bid < 8) {  // ---- wpack, rt = bid ----
    const int rt = bid;
    float* tile = (float*)smem;  // [32][260]
    const float4* src = (const float4*)(W + (size_t)rt * 32 * 256);
    #pragma unroll
    for (int it = 0; it < 8; ++it) {
      const int i = tid + 256 * it;
      float4 v = src[i];
      const int fi = 4 * i, row = fi >> 8, col = fi & 255;
      *(float4*)&tile[row * 260 + col] = v;
    }
    __syncthreads();
    const int w = tid >> 6, l = tid & 63, l31 = l & 31, h = l >> 5;
    unsigned short* dst = wp + (size_t)rt * 8192;
    #pragma unroll
    for (int ff = 0; ff < 4; ++ff) {
      const int f = 4 * w + ff;
      const float* rp = &tile[l31 * 260 + 16 * f + 8 * h];
      const float4 r0 = *(const float4*)rp;
      const float4 r1 = *(const float4*)(rp + 4);
      BF8 o;
      o.d[0] = f2bf2(r0.x, r0.y);
      o.d[1] = f2bf2(r0.z, r0.w);
      o.d[2] = f2bf2(r1.x, r1.y);
      o.d[3] = f2bf2(r1.z, r1.w);
      *(bf16x8*)(dst + (((size_t)f) * 64 + l) * 8) = o.v;
    }
  } else {  // ---- xtpack + sumsq ----
    const int e = bid - 8;
    const int mt = e % 36, kt = (e / 36) % 4, b = e / 144;
    const int m0 = mt * 64, k0 = kt * 64;
    float* tile = (float*)smem;              // [64][68] floats = 17408 B
    double* red = (double*)(smem + 17408);   // [4]
    const float* xb = x + (size_t)b * CHW;
    double ss = 0.0;
    #pragma unroll
    for (int it = 0; it < 4; ++it) {
      const int i = tid + 256 * it;
      const int row = i >> 4, c4 = (i & 15) * 4;
      float4 v = *(const float4*)(xb + (size_t)(k0 + row) * HW + m0 + c4);
      *(float4*)&tile[row * 68 + c4] = v;
      ss += (double)v.x * v.x + (double)v.y * v.y + (double)v.z * v.z + (double)v.w * v.w;
    }
    #pragma unroll
    for (int off = 32; off > 0; off >>= 1) ss += __shfl_down(ss, off, 64);
    const int w = tid >> 6, l = tid & 63;
    if (l == 0) red[w] = ss;
    __syncthreads();
    if (tid == 0) partials[b * 144 + kt * 36 + mt] = red[0] + red[1] + red[2] + red[3];
    const int l31 = l & 31, h = l >> 5;
    unsigned short* dst = xtp + (size_t)b * CHW;
    #pragma unroll
    for (int pp = 0; pp < 2; ++pp) {
      const int p = 2 * w + pp, mbl = p >> 2, fl = p & 3;
      BF8 o;
      #pragma unroll
      for (int jj = 0; jj < 4; ++jj) {
        const float e0 = tile[(16 * fl + 8 * h + 2 * jj) * 68 + 32 * mbl + l31];
        const float e1 = tile[(16 * fl + 8 * h + 2 * jj + 1) * 68 + 32 * mbl + l31];
        o.d[jj] = f2bf2(e0, e1);
      }
      const int mb = 2 * mt + mbl, f = 4 * kt + fl;
      *(bf16x8*)(dst + (((size_t)mb * 16 + f) * 64 + l) * 8) = o.v;
    }
  }
}

// ================= K2: conv3 — split by (b, rt, cb8); 1024 blocks x 576 thr; wp-based af (R16) =================
// Emission identity: unit (kfi, cb8) reads reshape cols c in [32cb8,+32) -> only mb = 8s+cb8.
// Wave w owns s = w: 16 MFMAs -> LDS band; emission 2 kfi units/wave (coalesced 1KB stores).
// af from packed wp (16 x 16B loads/lane = 16 MB total, vs R15's 288 MB W-direct regression).
__global__ __launch_bounds__(576) void conv3_kernel(const unsigned short* __restrict__ wp,
                                                    const float* __restrict__ bias,
                                                    const unsigned short* __restrict__ xtp,
                                                    unsigned short* __restrict__ trp,
                                                    const double* __restrict__ partials,
                                                    float* __restrict__ inv_xn2) {
  const int bid = blockIdx.x;
  if (bid == 1024) {  // ---- finish role: 1/xn^2 per batch ----
    const int t = threadIdx.x;
    if (t >= 128) return;
    const int b = t >> 3, i0 = t & 7;
    double v = 0.0;
    for (int i = i0; i < 144; i += 8) v += partials[b * 144 + i];
    v += __shfl_down(v, 4, 64);
    v += __shfl_down(v, 2, 64);
    v += __shfl_down(v, 1, 64);
    if (i0 == 0) inv_xn2[b] = (float)(1.0 / v);
    return;
  }
  const int xcd = bid & 7, r = bid >> 3;      // r in [0,128)
  const int b = xcd + 8 * (r & 1);            // 2 batches per XCD -> xtp[b] L2-resident
  const int r2 = r >> 1;                      // [0,64)
  const int rt = r2 >> 3, cb8 = r2 & 7;       // c'-tile of 32, c-col group of 32
  const int tid = threadIdx.x, w = tid >> 6, l = tid & 63, l31 = l & 31, h = l >> 5;
  const unsigned short* xb = xtp + (size_t)b * CHW;

  __shared__ unsigned short tile[32 * 296];   // [c'_local][32*s + l31, +8 pad]

  // A-frags from packed wp (shared by all 9 waves)
  bf16x8 af[16];
  #pragma unroll
  for (int f = 0; f < 16; ++f)
    af[f] = *(const bf16x8*)(wp + (((size_t)rt * 16 + f) * 64 + l) * 8);
  // bias per accumulator register
  float bcol[16];
  #pragma unroll
  for (int reg = 0; reg < 16; ++reg) {
    const int rowl = (reg & 3) + 8 * (reg >> 2) + 4 * h;
    bcol[reg] = bias[32 * rt + rowl];
  }

  // ---- MFMA phase: wave w owns s = w; mb = 8s + cb8; 16 MFMAs ----
  {
    const int s = w;
    const int mb = 8 * s + cb8;
    f32x16 acc;
    #pragma unroll
    for (int rr = 0; rr < 16; ++rr) acc[rr] = 0.f;
    #pragma unroll
    for (int f = 0; f < 16; ++f) {
      bf16x8 bv = *(const bf16x8*)(xb + (((size_t)mb * 16 + f) * 64 + l) * 8);
      acc = __builtin_amdgcn_mfma_f32_32x32x16_bf16(af[f], bv, acc, 0, 0, 0);
    }
    #pragma unroll
    for (int p = 0; p < 8; ++p) {
      const int r0 = 2 * p, r1 = 2 * p + 1;
      const int rowl = (r0 & 3) + 8 * (r0 >> 2) + 4 * h;  // r1's row = rowl + 1
      const unsigned pk = f2bf2(acc[r0] + bcol[r0], acc[r1] + bcol[r1]);
      tile[rowl * 296 + 32 * s + l31] = (unsigned short)pk;
      tile[(rowl + 1) * 296 + 32 * s + l31] = (unsigned short)(pk >> 16);
    }
  }
  __syncthreads();

  // ---- emission phase: 18 kfi units, 2 per wave; unit = coalesced 1KB trp store ----
  unsigned short* tb = trp + (size_t)b * CHW;
  #pragma unroll
  for (int si = 0; si < 2; ++si) {
    const int kfi = 2 * w + si;
    const int mbase = 288 * rt + 16 * kfi;     // 16-aligned reshaped-row base
    const int mb2 = mbase >> 6, kf = (mbase >> 4) & 3;
    BF8 o;
    #pragma unroll
    for (int j = 0; j < 8; ++j) {
      const int m = mbase + 8 * h + j;         // reshaped row
      const int a = m / 9, s = m - 9 * a;      // c' = a, band = s
      o.u[j] = tile[(a - 32 * rt) * 296 + 32 * s + l31];
    }
    *(bf16x8*)(tb + (size_t)mb2 * 16384 + (((size_t)cb8 * 4 + kf) * 64 + l) * 8) = o.v;
  }
}

// ================= K4: fused — R2-v3 schedule (CLOSED) + direct-x Af staging (R13) =================
// v3 core untouched: dbuf Pl, 1 barrier/chunk, reg-dbuf bv prefetch, LB(256,2), VGPR 128.
// Failed challengers (do not retry): sched_barrier/asm-waitcnt (R3 spill), setprio (R4 -8%),
// half-Af (R7 spill), single-Pl+LB3 (R8 spill), n128/4x-reuse (R10 -28%), single-Pl+LB2
// (R11 +7us). Cross-round noise band: +-4-7us (122.8..129.7 same code R13..R15).
#define CHUNK_BODY(CH, CUR, NXT)                                                                   \
  {                                                                                                \
    const int ch_ = (CH);                                                                          \
    const int pb_ = ch_ & 1;                                                                       \
    f32x16 s0, s1;                                                                                 \
    _Pragma("unroll")                                                                              \
    for (int i = 0; i < 16; ++i) { s0[i] = 0.f; s1[i] = 0.f; }                                     \
    _Pragma("unroll")                                                                              \
    for (int f = 0; f < 16; ++f) {                                                                 \
      bf16x8 a0 = *(const bf16x8*)(Af + f * 512 + lane * 8);                                       \
      bf16x8 a1 = *(const bf16x8*)(Af + (16 + f) * 512 + lane * 8);                                \
      s0 = __builtin_amdgcn_mfma_f32_32x32x16_bf16(a0, CUR[f], s0, 0, 0, 0);                       \
      s1 = __builtin_amdgcn_mfma_f32_32x32x16_bf16(a1, CUR[f], s1, 0, 0, 0);                       \
    }                                                                                              \
    bf16x8 bt0[8], bt1[8];                                                                         \
    _Pragma("unroll")                                                                              \
    for (int kk = 0; kk < 8; ++kk) {                                                               \
      const size_t mb_ = 2 * ch_ + (kk >> 2);                                                      \
      bt0[kk] = *(const bf16x8*)(ttb + mb_ * 16384 + ((size_t)((2 * c) * 4 + (kk & 3))) * 512 + lane * 8);     \
      bt1[kk] = *(const bf16x8*)(ttb + mb_ * 16384 + ((size_t)((2 * c + 1) * 4 + (kk & 3))) * 512 + lane * 8); \
    }                                                                                              \
    _Pragma("unroll")                                                                              \
    for (int reg = 0; reg < 16; ++reg) {                                                           \
      const int rowp = (reg & 3) + 8 * (reg >> 2) + 4 * h;                                         \
      float v0 = fmaxf(s0[reg] * inv2, 0.f); v0 *= v0;                                             \
      float v1 = fmaxf(s1[reg] * inv2, 0.f); v1 *= v1;                                             \
      Pl[pb_][rowp][32 * c + l31] = f2bf(v0);                                                      \
      Pl[pb_][32 + rowp][32 * c + l31] = f2bf(v1);                                                 \
    }                                                                                              \
    const int chn_ = (ch_ < 17) ? ch_ + 1 : 17;                                                    \
    const unsigned short* bpn_ = xtb + (size_t)((4 * chn_ + c) * 16) * 512 + lane * 8;             \
    _Pragma("unroll")                                                                              \
    for (int f = 0; f < 16; ++f) NXT[f] = *(const bf16x8*)(bpn_ + f * 512);                        \
    __syncthreads();                                                                               \
    _Pragma("unroll")                                                                              \
    for (int kk = 0; kk < 8; ++kk) {                                                               \
      bf16x8 pf0 = *(const bf16x8*)&Pl[pb_][l31][16 * kk + 8 * h];                                 \
      bf16x8 pf1 = *(const bf16x8*)&Pl[pb_][32 + l31][16 * kk + 8 * h];                            \
      yacc[0][0] = __builtin_amdgcn_mfma_f32_32x32x16_bf16(pf0, bt0[kk], yacc[0][0], 0, 0, 0);     \
      yacc[1][0] = __builtin_amdgcn_mfma_f32_32x32x16_bf16(pf1, bt0[kk], yacc[1][0], 0, 0, 0);     \
      yacc[0][1] = __builtin_amdgcn_mfma_f32_32x32x16_bf16(pf0, bt1[kk], yacc[0][1], 0, 0, 0);     \
      yacc[1][1] = __builtin_amdgcn_mfma_f32_32x32x16_bf16(pf1, bt1[kk], yacc[1][1], 0, 0, 0);     \
    }                                                                                              \
  }

__global__ __launch_bounds__(256, 2) void fused_kernel(const float* __restrict__ x,
                                                       const unsigned short* __restrict__ xtp,
                                                       const unsigned short* __restrict__ trp,
                                                       const float* __restrict__ inv_xn2,
                                                       float* __restrict__ out) {
  const int bid = blockIdx.x;
  const int xcd = bid & 7, j = bid >> 3;     // j in [0,72)
  const int hi = (j >= 36) ? 1 : 0;
  const int b = xcd + 8 * hi;                // one batch per XCD at a time
  const int nt = j - 36 * hi;                // [0,36) n-tile of 64 rows
  const float* xsrc = x + (size_t)b * CHW;
  const unsigned short* xtb = xtp + (size_t)b * CHW;
  const unsigned short* ttb = trp + (size_t)b * CHW;
  float* ob = out + (size_t)b * CHW;
  const float inv2 = inv_xn2[b];

  const int tid = threadIdx.x;
  const int c = tid >> 6, lane = tid & 63;   // wave c = S-col / Y-col group
  const int l31 = lane & 31, h = lane >> 5;

  __shared__ unsigned short Af[16384];       // 2 n-halves x 16 A-frags x 512 shorts (32 KB)
  __shared__ unsigned short Pl[2][64][136];  // double-buffered P (34.0 KB)

  {  // stage Af DIRECTLY from x: fragment (f,l) = 32 contiguous bytes of x at
     // row n = 64*nt + 32*(f>>4) + (l&31), col 16*(f&15) + 8*(l>>5)   [R13]
    #pragma unroll
    for (int it = 0; it < 8; ++it) {
      const int idx = tid + 256 * it;        // [0,2048) = (f in [0,32)) x (l in [0,64))
      const int f = idx >> 6, l = idx & 63;
      const int ll31 = l & 31, hh = l >> 5;
      const float* sp = xsrc + (size_t)(64 * nt + 32 * (f >> 4) + ll31) * 256 + 16 * (f & 15) + 8 * hh;
      const float4 r0 = *(const float4*)sp;
      const float4 r1 = *(const float4*)(sp + 4);
      BF8 o;
      o.d[0] = f2bf2(r0.x, r0.y);
      o.d[1] = f2bf2(r0.z, r0.w);
      o.d[2] = f2bf2(r1.x, r1.y);
      o.d[3] = f2bf2(r1.z, r1.w);
      *(bf16x8*)(Af + (size_t)f * 512 + (size_t)l * 8) = o.v;
    }
  }

  // prologue: chunk 0's S B-frags (issued before the staging barrier; independent of LDS)
  bf16x8 bva[16], bvb[16];
  {
    const unsigned short* bp0 = xtb + (size_t)(c * 16) * 512 + lane * 8;
    #pragma unroll
    for (int f = 0; f < 16; ++f) bva[f] = *(const bf16x8*)(bp0 + f * 512);
  }
  __syncthreads();

  f32x16 yacc[2][2];  // [n-half][cb]
  #pragma unroll
  for (int nh = 0; nh < 2; ++nh)
    #pragma unroll
    for (int cb = 0; cb < 2; ++cb)
      #pragma unroll
      for (int i = 0; i < 16; ++i) yacc[nh][cb][i] = 0.f;

  for (int ci = 0; ci < 9; ++ci) {  // 18 chunks, explicit 2x alternation of bva/bvb (rule #20)
    CHUNK_BODY(2 * ci, bva, bvb)
    CHUNK_BODY(2 * ci + 1, bvb, bva)
  }

  // ---- epilogue: out flat at ob[n*256 + k'] ----
  #pragma unroll
  for (int nh = 0; nh < 2; ++nh)
    #pragma unroll
    for (int cb = 0; cb < 2; ++cb) {
      const int col = 64 * c + 32 * cb + l31;
      #pragma unroll
      for (int reg = 0; reg < 16; ++reg) {
        const int rowp = (reg & 3) + 8 * (reg >> 2) + 4 * h;
        ob[(size_t)(64 * nt + 32 * nh + rowp) * NC + col] = yacc[nh][cb][reg];
      }
    }
}

extern "C" void kernel_launch(void* const* d_in, const int* in_sizes, int n_in,
                              void* d_out, int out_size, void* d_ws, size_t ws_size,
                              hipStream_t stream) {
  const float* x    = (const float*)d_in[0];
  const float* W    = (const float*)d_in[1];
  const float* bias = (const float*)d_in[2];
  float* out = (float*)d_out;

  const size_t SZ = (size_t)NB * CHW * sizeof(unsigned short);  // 18,874,368 B
  double* partials       = (double*)d_ws;                           // 16*144*8 = 18,432 B
  float* inv_xn2         = (float*)((char*)d_ws + 24576);
  unsigned short* wp     = (unsigned short*)((char*)d_ws + 32768);  // 128 KB
  unsigned short* xtp    = (unsigned short*)((char*)d_ws + 163840 + SZ);
  unsigned short* trp    = (unsigned short*)((char*)d_ws + 163840 + 3 * SZ);

  prep_kernel<<<2312, 256, 0, stream>>>(x, W, wp, xtp, partials);
  conv3_kernel<<<1025, 576, 0, stream>>>(wp, bias, xtp, trp, partials, inv_xn2);
  fused_kernel<<<576, 256, 0, stream>>>(x, xtp, trp, inv_xn2, out);
}